// Round 9
// baseline (650.527 us; speedup 1.0000x reference)
//
#include <hip/hip_runtime.h>
#include <hip/hip_bf16.h>
#include <stdint.h>

typedef __bf16 bf16x8 __attribute__((ext_vector_type(8)));
typedef float f32x16 __attribute__((ext_vector_type(16)));

// ---- helpers ------------------------------------------------------------

__device__ inline void gload_lds16(const void* g, void* lds) {
  __builtin_amdgcn_global_load_lds(
      (const __attribute__((address_space(1))) uint32_t*)(uintptr_t)g,
      (__attribute__((address_space(3))) uint32_t*)(uintptr_t)lds,
      16, 0, 0);
}

// Ordered ds_read_b128 with literal byte offset (issue order preserved;
// DS completion in-order per wave -> counted lgkmcnt exact).
#define DSR(dst, base, OFF)                                         \
  asm volatile("ds_read_b128 %0, %1 offset:" #OFF                   \
               : "=v"(dst) : "v"(base))
#define RD4(arr, base, OFF) do {                                    \
    DSR(arr[0], base[0], OFF); DSR(arr[1], base[1], OFF);           \
    DSR(arr[2], base[2], OFF); DSR(arr[3], base[3], OFF);           \
  } while (0)

#define LGKM(N) do {                                             \
    asm volatile("s_waitcnt lgkmcnt(" #N ")" ::: "memory");      \
    __builtin_amdgcn_sched_barrier(0);                           \
  } while (0)
#define VM(N) do {                                               \
    asm volatile("s_waitcnt vmcnt(" #N ")" ::: "memory");        \
    __builtin_amdgcn_sched_barrier(0);                           \
  } while (0)

__device__ inline short f2bf(float f) {
  union { float f; uint32_t u; } x; x.f = f;
  uint32_t u = x.u;
  u += 0x7fffu + ((u >> 16) & 1u);   // RNE
  return (short)(u >> 16);
}

#define BAR() do { asm volatile("" ::: "memory"); \
                   __builtin_amdgcn_s_barrier();  \
                   asm volatile("" ::: "memory"); } while (0)

// ---- fp32 -> bf16 convert (vectorized) ----------------------------------

__global__ __launch_bounds__(256) void cvt_f32_bf16(
    const float* __restrict__ in, short* __restrict__ out, int n4) {
  int i = blockIdx.x * 256 + threadIdx.x;
  if (i < n4) {
    float4 v = reinterpret_cast<const float4*>(in)[i];
    short4 o;
    o.x = f2bf(v.x); o.y = f2bf(v.y); o.z = f2bf(v.z); o.w = f2bf(v.w);
    reinterpret_cast<short4*>(out)[i] = o;
  }
}

// ---- GEMM: C[M,N] = A[M,K] @ B[N,K]^T, bf16 in, fp32 acc ---------------
// r8's 8-phase barrier-crossing schedule + 32x32x16 MFMA (higher issue
// efficiency: 2382 vs 2075 TF ubench) + r3's once-per-K-tile vmcnt(6).
//
// 256x256 tile, BK=64, 8 waves (2Mx4N), per-wave 128x64 = 4(M) x 2(N)
// frags of 32x32, acc = f32x16[4][2].
// LDS: 2 buf x 4 slots x [128x64] bf16 = 128 KiB (unchanged layout):
//   A0 rows {0-63,128-191}, A1 {64-127,192-255}, B0 cols wc*64+[0,32),
//   B1 cols wc*64+[32,64); granule swizzle P = g ^ (r&7) (0-conflict,
//   verified r2-r8).
// Fragment reads (32x32x16): row = base + (lane&31), k-granule =
//   ks*2 + (lane>>5); mf0 at offset 0, mf1 +4096, mf2 +16384, mf3
//   +20480 (A); nf0 +0, nf1 +16384 (B, base incl. +32768 slot).
//   8 address regs, buf switch = +/-65536 mutation per tile.
// Phases per K-tile t (cur=t&1, nxt=cur^1):
//   Ph1: rd a01(8)+b0(4) | stage A1(t+1)->nxt | LGKM(8) BAR LGKM(0)
//        prio 8xMFMA Q1(m01,n0) | BAR
//   Ph2: rd b1(4) | stage A0(t+2)->cur | BAR LGKM(0) Q2(m01,n1) | BAR
//   Ph3: rd a23(8) | stage B0(t+2)->cur | BAR LGKM(0) Q3(m23,n1) | BAR
//   Ph4: stage B1(t+2)->cur | BAR Q4(m23,n0) | VM(6) BAR
// Ledgers (r3-verified): clobber — every slot restage >= 1 closing
// barrier after that slot's reads completed (LGKM(0) precedes same
// phase's close); readiness — at Ph4 close, vmcnt(6) leaves only
// {A0,B0,B1}(t+2) in flight, so tile t+1's 4 half-tiles are complete
// before the publishing barrier. Tail: t==nk-2 uses VM(0).
// MFMA operands SWAPPED (mfma(b,a)): D col=lane&31 -> M-row; D reg
// (reg&3)+8*(reg>>2)+4*(lane>>5) -> N-col offset; reg groups of 4 =
// 4 consecutive cols -> vectorized stores (m74/m101-verified map).
// EPI=0: bias+relu^2->bf16 (short4); EPI=1: bias->f32 (float4).

template <int EPI>
__global__ __launch_bounds__(512, 2) void gemm_bt(
    const short* __restrict__ A, const short* __restrict__ B,
    const float* __restrict__ bias, void* __restrict__ Cout,
    int M, int N, int K) {
  __shared__ __align__(16) short lds[2][4][128 * 64];

  const int tid  = threadIdx.x;
  const int wave = tid >> 6;
  const int lane = tid & 63;
  const int wr = wave >> 2;          // 0..1 -> M half (128 rows)
  const int wc = wave & 3;           // 0..3 -> N quarter (64 cols)
  const int l31 = lane & 31, kh = lane >> 5;

  // T1: bijective XCD swizzle (nwg % 8 == 0), column-major in-chunk
  const int nwg = gridDim.x;
  const int w = (blockIdx.x & 7) * (nwg >> 3) + (blockIdx.x >> 3);
  const int gy = M >> 8;
  const int brow = w % gy;
  const int bcol = w / gy;

  f32x16 acc[4][2];
#pragma unroll
  for (int m = 0; m < 4; ++m)
#pragma unroll
    for (int n = 0; n < 2; ++n) {
      f32x16 z = {0.f};
      acc[m][n] = z;
    }

  const int nk = K >> 6;             // K-tiles of 64

  // ---- fragment read base addresses (buf0), 8 regs, mutate per tile
  const uint32_t LB = (uint32_t)(uintptr_t)&lds[0][0][0];
  uint32_t aT[4], bT[4];
  {
    const int r  = wr * 64 + l31;          // A mf0 row
    const int x  = r & 7;
    const int rb = wc * 32 + l31;          // B nf0 row
    const int xb = rb & 7;
#pragma unroll
    for (int ks = 0; ks < 4; ++ks) {
      aT[ks] = LB + (uint32_t)(r * 128 + (((ks * 2 + kh) ^ x) * 16));
      bT[ks] = LB + 32768u +
               (uint32_t)(rb * 128 + (((ks * 2 + kh) ^ xb) * 16));
    }
  }

  // ---- stage source addressing (inverse swizzle on global side)
  const int i0 = tid;
  const int gl0 = i0 ^ ((i0 >> 3) & 7);
  const int r0 = gl0 >> 3, c0 = gl0 & 7;
  const size_t rstep = (size_t)128 * K;

  const short* pA[2];
  const short* pB[2];
  {
    const int rb0 = (r0 >> 5) * 64 + (r0 & 31);
#pragma unroll
    for (int h = 0; h < 2; ++h) {
      pA[h] = A + (size_t)(brow * 256 + h * 64 + r0) * K + c0 * 8;
      pB[h] = B + (size_t)(bcol * 256 + rb0 + h * 32) * K + c0 * 8;
    }
  }

  const int dst0 = wave * 512, dst1 = 4096 + wave * 512;  // shorts in slot

#define STAGE(p, buf, slot)                              \
  do {                                                   \
    short* base_ = &lds[buf][slot][0];                   \
    gload_lds16((p), base_ + dst0);                      \
    gload_lds16((p) + rstep, base_ + dst1);              \
    (p) += 64;                                           \
  } while (0)

  // fragment regs + quadrant clusters (swapped operands, static indices)
  bf16x8 a01[2][4], a23[2][4], b0[4], b1[4];
  auto Q1 = [&]() {
#pragma unroll
    for (int mi = 0; mi < 2; ++mi)
#pragma unroll
      for (int ks = 0; ks < 4; ++ks)
        acc[mi][0] = __builtin_amdgcn_mfma_f32_32x32x16_bf16(
            b0[ks], a01[mi][ks], acc[mi][0], 0, 0, 0);
  };
  auto Q2 = [&]() {
#pragma unroll
    for (int mi = 0; mi < 2; ++mi)
#pragma unroll
      for (int ks = 0; ks < 4; ++ks)
        acc[mi][1] = __builtin_amdgcn_mfma_f32_32x32x16_bf16(
            b1[ks], a01[mi][ks], acc[mi][1], 0, 0, 0);
  };
  auto Q3 = [&]() {
#pragma unroll
    for (int mi = 0; mi < 2; ++mi)
#pragma unroll
      for (int ks = 0; ks < 4; ++ks)
        acc[2 + mi][1] = __builtin_amdgcn_mfma_f32_32x32x16_bf16(
            b1[ks], a23[mi][ks], acc[2 + mi][1], 0, 0, 0);
  };
  auto Q4 = [&]() {
#pragma unroll
    for (int mi = 0; mi < 2; ++mi)
#pragma unroll
      for (int ks = 0; ks < 4; ++ks)
        acc[2 + mi][0] = __builtin_amdgcn_mfma_f32_32x32x16_bf16(
            b0[ks], a23[mi][ks], acc[2 + mi][0], 0, 0, 0);
  };

#define PRIO_ON  __builtin_amdgcn_s_setprio(1)
#define PRIO_OFF __builtin_amdgcn_s_setprio(0)

  // ---- prologue: tile0 full + tile1 {A0,B0,B1}; publish tile 0.
  STAGE(pA[0], 0, 0);   // A0(0)
  STAGE(pB[0], 0, 2);   // B0(0)
  STAGE(pB[1], 0, 3);   // B1(0)
  STAGE(pA[1], 0, 1);   // A1(0)
  STAGE(pA[0], 1, 0);   // A0(1)
  STAGE(pB[0], 1, 2);   // B0(1)
  STAGE(pB[1], 1, 3);   // B1(1)
  VM(6);                // tile 0 (oldest 8 loads) landed
  BAR();

  for (int t = 0; t < nk; ++t) {
    const int cur = t & 1, nxt = cur ^ 1;
    const bool s1 = (t + 1) < nk, g2 = (t + 2) < nk;
    if (t) {           // switch read addresses to buf[cur]
      const int32_t d = cur ? 65536 : -65536;
#pragma unroll
      for (int ks = 0; ks < 4; ++ks) { aT[ks] += d; bT[ks] += d; }
    }

    // Ph1: rd a01(8)+b0(4) | stage A1(t+1)
    RD4(a01[0], aT, 0);
    RD4(a01[1], aT, 4096);
    RD4(b0, bT, 0);
    if (s1) STAGE(pA[1], nxt, 1);
    LGKM(8);
    BAR();
    LGKM(0);
    PRIO_ON; Q1(); PRIO_OFF;
    BAR();

    // Ph2: rd b1(4) | stage A0(t+2)
    RD4(b1, bT, 16384);
    if (g2) STAGE(pA[0], cur, 0);
    BAR();
    LGKM(0);
    PRIO_ON; Q2(); PRIO_OFF;
    BAR();

    // Ph3: rd a23(8) | stage B0(t+2)
    RD4(a23[0], aT, 16384);
    RD4(a23[1], aT, 20480);
    if (g2) STAGE(pB[0], cur, 2);
    BAR();
    LGKM(0);
    PRIO_ON; Q3(); PRIO_OFF;
    BAR();

    // Ph4: stage B1(t+2) | Q4 | per-tile counted publish
    if (g2) STAGE(pB[1], cur, 3);
    BAR();
    PRIO_ON; Q4(); PRIO_OFF;
    if (g2)      { VM(6); }
    else if (s1) { VM(0); }
    if (s1) BAR();
  }

  // ---- epilogue: lane&31 = M-row; reg group g -> cols 8g+4hi+{0..3}
  const int hi = lane >> 5;
  if (EPI == 0) {
    short* C = (short*)Cout;
#pragma unroll
    for (int mf = 0; mf < 4; ++mf) {
      const int row = brow * 256 + wr * 128 + mf * 32 + l31;
#pragma unroll
      for (int nf = 0; nf < 2; ++nf) {
        const int colb = bcol * 256 + wc * 64 + nf * 32 + hi * 4;
#pragma unroll
        for (int g = 0; g < 4; ++g) {
          const int col = colb + g * 8;
          const float4 bv = *(const float4*)&bias[col];
          short4 o;
          float v0 = acc[mf][nf][4 * g + 0] + bv.x; v0 = v0 > 0.f ? v0 * v0 : 0.f;
          float v1 = acc[mf][nf][4 * g + 1] + bv.y; v1 = v1 > 0.f ? v1 * v1 : 0.f;
          float v2 = acc[mf][nf][4 * g + 2] + bv.z; v2 = v2 > 0.f ? v2 * v2 : 0.f;
          float v3 = acc[mf][nf][4 * g + 3] + bv.w; v3 = v3 > 0.f ? v3 * v3 : 0.f;
          o.x = f2bf(v0); o.y = f2bf(v1); o.z = f2bf(v2); o.w = f2bf(v3);
          *(short4*)&C[(size_t)row * N + col] = o;
        }
      }
    }
  } else {
    float* C = (float*)Cout;
#pragma unroll
    for (int mf = 0; mf < 4; ++mf) {
      const int row = brow * 256 + wr * 128 + mf * 32 + l31;
#pragma unroll
      for (int nf = 0; nf < 2; ++nf) {
        const int colb = bcol * 256 + wc * 64 + nf * 32 + hi * 4;
#pragma unroll
        for (int g = 0; g < 4; ++g) {
          const int col = colb + g * 8;
          const float4 bv = *(const float4*)&bias[col];
          float4 o;
          o.x = acc[mf][nf][4 * g + 0] + bv.x;
          o.y = acc[mf][nf][4 * g + 1] + bv.y;
          o.z = acc[mf][nf][4 * g + 2] + bv.z;
          o.w = acc[mf][nf][4 * g + 3] + bv.w;
          *(float4*)&C[(size_t)row * N + col] = o;
        }
      }
    }
  }
#undef STAGE
}

// ---- launch -------------------------------------------------------------

extern "C" void kernel_launch(void* const* d_in, const int* in_sizes, int n_in,
                              void* d_out, int out_size, void* d_ws,
                              size_t ws_size, hipStream_t stream) {
  const float* x  = (const float*)d_in[0];
  const float* w1 = (const float*)d_in[1];
  const float* b1 = (const float*)d_in[2];
  const float* w2 = (const float*)d_in[3];
  const float* b2 = (const float*)d_in[4];
  float* out = (float*)d_out;

  const int H = in_sizes[2];            // 8192
  const int D = in_sizes[4];            // 2048
  const int M = in_sizes[0] / D;        // B*S = 8192

  short* xb  = (short*)d_ws;                 // M*D
  short* w1b = xb  + (size_t)M * D;          // H*D
  short* w2b = w1b + (size_t)H * D;          // D*H
  short* act = w2b + (size_t)D * H;          // M*H

  {
    int n4 = (M * D) / 4;
    cvt_f32_bf16<<<(n4 + 255) / 256, 256, 0, stream>>>(x, xb, n4);
    n4 = (H * D) / 4;
    cvt_f32_bf16<<<(n4 + 255) / 256, 256, 0, stream>>>(w1, w1b, n4);
    n4 = (D * H) / 4;
    cvt_f32_bf16<<<(n4 + 255) / 256, 256, 0, stream>>>(w2, w2b, n4);
  }

  // GEMM1: [M,D] @ [H,D]^T -> sqrelu -> act[M,H] (bf16)
  gemm_bt<0><<<(M / 256) * (H / 256), 512, 0, stream>>>(
      xb, w1b, b1, (void*)act, M, H, D);
  // GEMM2: [M,H] @ [D,H]^T -> + b2 -> out[M,D] (f32)
  gemm_bt<1><<<(M / 256) * (D / 256), 512, 0, stream>>>(
      act, w2b, b2, (void*)out, M, D, H);
}

// Round 10
// 547.920 us; speedup vs baseline: 1.1873x; 1.1873x over previous
//
#include <hip/hip_runtime.h>
#include <hip/hip_bf16.h>
#include <stdint.h>

typedef __bf16 bf16x8 __attribute__((ext_vector_type(8)));
typedef float f32x4 __attribute__((ext_vector_type(4)));

// ---- helpers ------------------------------------------------------------

__device__ inline void gload_lds16(const void* g, void* lds) {
  __builtin_amdgcn_global_load_lds(
      (const __attribute__((address_space(1))) uint32_t*)(uintptr_t)g,
      (__attribute__((address_space(3))) uint32_t*)(uintptr_t)lds,
      16, 0, 0);
}

// Ordered ds_read_b128, base reg + literal offset (issue order preserved;
// DS completion in-order per wave -> counted lgkmcnt exact).
#define DSR(dst, base, OFF)                                         \
  asm volatile("ds_read_b128 %0, %1 offset:" #OFF                   \
               : "=v"(dst) : "v"(base))

#define LGKM(N) do {                                             \
    asm volatile("s_waitcnt lgkmcnt(" #N ")" ::: "memory");      \
    __builtin_amdgcn_sched_barrier(0);                           \
  } while (0)
#define VM(N) do {                                               \
    asm volatile("s_waitcnt vmcnt(" #N ")" ::: "memory");        \
    __builtin_amdgcn_sched_barrier(0);                           \
  } while (0)

__device__ inline short f2bf(float f) {
  union { float f; uint32_t u; } x; x.f = f;
  uint32_t u = x.u;
  u += 0x7fffu + ((u >> 16) & 1u);   // RNE
  return (short)(u >> 16);
}

#define BAR() do { asm volatile("" ::: "memory"); \
                   __builtin_amdgcn_s_barrier();  \
                   asm volatile("" ::: "memory"); } while (0)

// ---- fp32 -> bf16 convert (vectorized) ----------------------------------

__global__ __launch_bounds__(256) void cvt_f32_bf16(
    const float* __restrict__ in, short* __restrict__ out, int n4) {
  int i = blockIdx.x * 256 + threadIdx.x;
  if (i < n4) {
    float4 v = reinterpret_cast<const float4*>(in)[i];
    short4 o;
    o.x = f2bf(v.x); o.y = f2bf(v.y); o.z = f2bf(v.z); o.w = f2bf(v.w);
    reinterpret_cast<short4*>(out)[i] = o;
  }
}

// ---- GEMM: C[M,N] = A[M,K] @ B[N,K]^T, bf16 in, fp32 acc ---------------
// r8's 16x16 barrier-crossing 8-phase schedule (0 bank conflicts) +
// r9's verified once-per-K-tile vmcnt(6) and flag-based tail.
//
// 256x256 tile, BK=64, 8 waves (2Mx4N), per-wave 128x64 = acc[8][4] of
// mfma_f32_16x16x32_bf16 (swapped operands).
// LDS: 2 buf x 4 slots x [128x64] bf16 = 128 KiB:
//   A0 rows{0-63,128-191} (+0), A1 rows{64-127,192-255} (+16384),
//   B0 n-frags 0-1 (+32768), B1 n-frags 2-3 (+49152); buf1 = +65536.
// Swizzle P = g ^ (r&7) == addr = slotrow*128 + ((kk*4+kq)^(fr&7))*16
// (identity proven: r&7 == fr&7 since wr*64, m*16 are 0 mod 8; g low3 =
// kk*4+kq). 4 base regs bA[2]/bB[2] (kk=0,1); m/n-frag step = +2048
// literal; A1/B1 = +16384 literal; per-tile buf switch = +/-65536.
// Phases per K-tile t (cur=t&1, nxt=cur^1):
//   Ph1: rd a0q(8)+bq0(4) | stage A1(t+1)->nxt | LGKM(8) BAR LGKM(0)
//        prio Q1(m0-3,n0-1) | BAR
//   Ph2: rd bq1(4) | stage A0(t+2)->cur | BAR LGKM(0) Q2(m0-3,n2-3) | BAR
//   Ph3: rd a1q(8) | stage B0(t+2)->cur | BAR LGKM(0) Q3(m4-7,n2-3) | BAR
//   Ph4: stage B1(t+2)->cur | BAR Q4(m4-7,n0-1) | VM(6) BAR
// Ledgers (r3/r9-verified): clobber — every slot restage is >=1 closing
// barrier after that slot's reads completed (LGKM(0) precedes the same
// phase's close). Readiness — VM(6) at Ph4 leaves only {A0,B0,B1}(t+2)
// (6 gloads) in flight -> tile t+1 fully landed before the publishing
// barrier. Tail flags: g2 ? VM(6) : s1 ? VM(0); last tile no sync.
// Epilogue (verified r5-r8): lane&15=M-row, 4 acc regs = 4 consecutive
// N-cols. EPI=0: bias+relu^2->bf16 (short4); EPI=1: bias->f32 (float4).

template <int EPI>
__global__ __launch_bounds__(512, 2) void gemm_bt(
    const short* __restrict__ A, const short* __restrict__ B,
    const float* __restrict__ bias, void* __restrict__ Cout,
    int M, int N, int K) {
  __shared__ __align__(16) short lds[2][4][128 * 64];

  const int tid  = threadIdx.x;
  const int wave = tid >> 6;
  const int lane = tid & 63;
  const int wr = wave >> 2;          // 0..1 -> M half (128 rows)
  const int wc = wave & 3;           // 0..3 -> N quarter (64 cols)
  const int fr = lane & 15, kq = lane >> 4;

  // T1: bijective XCD swizzle (nwg % 8 == 0), column-major in-chunk
  const int nwg = gridDim.x;
  const int w = (blockIdx.x & 7) * (nwg >> 3) + (blockIdx.x >> 3);
  const int gy = M >> 8;
  const int brow = w % gy;
  const int bcol = w / gy;

  f32x4 acc[8][4];
#pragma unroll
  for (int m = 0; m < 8; ++m)
#pragma unroll
    for (int n = 0; n < 4; ++n)
      acc[m][n] = (f32x4){0.f, 0.f, 0.f, 0.f};

  const int nk = K >> 6;             // K-tiles of 64

  // ---- fragment read base addresses (buf0); 4 regs, mutate per tile
  const uint32_t LB = (uint32_t)(uintptr_t)&lds[0][0][0];
  uint32_t bA[2], bB[2];
  {
    const uint32_t x0 = (uint32_t)(((kq)     ^ (fr & 7)) * 16);
    const uint32_t x1 = (uint32_t)(((4 + kq) ^ (fr & 7)) * 16);
    const uint32_t ra = (uint32_t)((wr * 64 + fr) * 128);
    const uint32_t rb = (uint32_t)((wc * 32 + fr) * 128);
    bA[0] = LB + ra + x0;            bA[1] = LB + ra + x1;
    bB[0] = LB + 32768u + rb + x0;   bB[1] = LB + 32768u + rb + x1;
  }

  // ---- stage source addressing (inverse swizzle on global side)
  const int i0 = tid;
  const int gl0 = i0 ^ ((i0 >> 3) & 7);
  const int r0 = gl0 >> 3, c0 = gl0 & 7;
  const size_t rstep = (size_t)128 * K;

  const short* pA[2];
  const short* pB[2];
  {
    const int rb0 = (r0 >> 5) * 64 + (r0 & 31);
#pragma unroll
    for (int h = 0; h < 2; ++h) {
      pA[h] = A + (size_t)(brow * 256 + h * 64 + r0) * K + c0 * 8;
      pB[h] = B + (size_t)(bcol * 256 + rb0 + h * 32) * K + c0 * 8;
    }
  }

  const int dst0 = wave * 512, dst1 = 4096 + wave * 512;  // shorts in slot

#define STAGE(p, buf, slot)                              \
  do {                                                   \
    short* base_ = &lds[buf][slot][0];                   \
    gload_lds16((p), base_ + dst0);                      \
    gload_lds16((p) + rstep, base_ + dst1);              \
    (p) += 64;                                           \
  } while (0)

  // fragment regs + quadrant clusters (swapped operands)
  bf16x8 a0q[4][2], a1q[4][2], bq0[2][2], bq1[2][2];
  auto Q1 = [&]() {
#pragma unroll
    for (int m = 0; m < 4; ++m)
#pragma unroll
      for (int n = 0; n < 2; ++n)
#pragma unroll
        for (int kk = 0; kk < 2; ++kk)
          acc[m][n] = __builtin_amdgcn_mfma_f32_16x16x32_bf16(
              bq0[n][kk], a0q[m][kk], acc[m][n], 0, 0, 0);
  };
  auto Q2 = [&]() {
#pragma unroll
    for (int m = 0; m < 4; ++m)
#pragma unroll
      for (int n = 0; n < 2; ++n)
#pragma unroll
        for (int kk = 0; kk < 2; ++kk)
          acc[m][n + 2] = __builtin_amdgcn_mfma_f32_16x16x32_bf16(
              bq1[n][kk], a0q[m][kk], acc[m][n + 2], 0, 0, 0);
  };
  auto Q3 = [&]() {
#pragma unroll
    for (int m = 0; m < 4; ++m)
#pragma unroll
      for (int n = 0; n < 2; ++n)
#pragma unroll
        for (int kk = 0; kk < 2; ++kk)
          acc[m + 4][n + 2] = __builtin_amdgcn_mfma_f32_16x16x32_bf16(
              bq1[n][kk], a1q[m][kk], acc[m + 4][n + 2], 0, 0, 0);
  };
  auto Q4 = [&]() {
#pragma unroll
    for (int m = 0; m < 4; ++m)
#pragma unroll
      for (int n = 0; n < 2; ++n)
#pragma unroll
        for (int kk = 0; kk < 2; ++kk)
          acc[m + 4][n] = __builtin_amdgcn_mfma_f32_16x16x32_bf16(
              bq0[n][kk], a1q[m][kk], acc[m + 4][n], 0, 0, 0);
  };

#define PRIO_ON  __builtin_amdgcn_s_setprio(1)
#define PRIO_OFF __builtin_amdgcn_s_setprio(0)

  // ---- prologue: tile0 full + tile1 {A0,B0,B1}; publish tile 0.
  STAGE(pA[0], 0, 0);   // A0(0)
  STAGE(pB[0], 0, 2);   // B0(0)
  STAGE(pB[1], 0, 3);   // B1(0)
  STAGE(pA[1], 0, 1);   // A1(0)
  STAGE(pA[0], 1, 0);   // A0(1)
  STAGE(pB[0], 1, 2);   // B0(1)
  STAGE(pB[1], 1, 3);   // B1(1)
  VM(6);                // tile 0 (oldest 8 gloads) landed
  BAR();

  for (int t = 0; t < nk; ++t) {
    const int cur = t & 1, nxt = cur ^ 1;
    const bool s1 = (t + 1) < nk, g2 = (t + 2) < nk;
    if (t) {           // switch read bases to buf[cur]
      const int32_t d = cur ? 65536 : -65536;
      bA[0] += d; bA[1] += d; bB[0] += d; bB[1] += d;
    }

    // Ph1: rd a0q(8)+bq0(4) | stage A1(t+1)
    DSR(a0q[0][0], bA[0], 0);     DSR(a0q[0][1], bA[1], 0);
    DSR(a0q[1][0], bA[0], 2048);  DSR(a0q[1][1], bA[1], 2048);
    DSR(a0q[2][0], bA[0], 4096);  DSR(a0q[2][1], bA[1], 4096);
    DSR(a0q[3][0], bA[0], 6144);  DSR(a0q[3][1], bA[1], 6144);
    DSR(bq0[0][0], bB[0], 0);     DSR(bq0[0][1], bB[1], 0);
    DSR(bq0[1][0], bB[0], 2048);  DSR(bq0[1][1], bB[1], 2048);
    if (s1) STAGE(pA[1], nxt, 1);
    LGKM(8);
    BAR();
    LGKM(0);
    PRIO_ON; Q1(); PRIO_OFF;
    BAR();

    // Ph2: rd bq1(4) | stage A0(t+2)
    DSR(bq1[0][0], bB[0], 16384); DSR(bq1[0][1], bB[1], 16384);
    DSR(bq1[1][0], bB[0], 18432); DSR(bq1[1][1], bB[1], 18432);
    if (g2) STAGE(pA[0], cur, 0);
    BAR();
    LGKM(0);
    PRIO_ON; Q2(); PRIO_OFF;
    BAR();

    // Ph3: rd a1q(8) | stage B0(t+2)
    DSR(a1q[0][0], bA[0], 16384); DSR(a1q[0][1], bA[1], 16384);
    DSR(a1q[1][0], bA[0], 18432); DSR(a1q[1][1], bA[1], 18432);
    DSR(a1q[2][0], bA[0], 20480); DSR(a1q[2][1], bA[1], 20480);
    DSR(a1q[3][0], bA[0], 22528); DSR(a1q[3][1], bA[1], 22528);
    if (g2) STAGE(pB[0], cur, 2);
    BAR();
    LGKM(0);
    PRIO_ON; Q3(); PRIO_OFF;
    BAR();

    // Ph4: stage B1(t+2) | Q4 | per-tile counted publish
    if (g2) STAGE(pB[1], cur, 3);
    BAR();
    PRIO_ON; Q4(); PRIO_OFF;
    if (g2)      { VM(6); }
    else if (s1) { VM(0); }
    if (s1) BAR();
  }

  // ---- epilogue (verified r5-r8): row = m*16+fr, cols = n*16+q*4+{0..3}
  const int q = lane >> 4;
  if (EPI == 0) {
    short* C = (short*)Cout;
#pragma unroll
    for (int m = 0; m < 8; ++m) {
      const int row = brow * 256 + wr * 128 + m * 16 + fr;
#pragma unroll
      for (int n = 0; n < 4; ++n) {
        const int col = bcol * 256 + wc * 64 + n * 16 + q * 4;
        const float4 bv = *(const float4*)&bias[col];
        short4 o;
        float v0 = acc[m][n][0] + bv.x; v0 = v0 > 0.f ? v0 * v0 : 0.f;
        float v1 = acc[m][n][1] + bv.y; v1 = v1 > 0.f ? v1 * v1 : 0.f;
        float v2 = acc[m][n][2] + bv.z; v2 = v2 > 0.f ? v2 * v2 : 0.f;
        float v3 = acc[m][n][3] + bv.w; v3 = v3 > 0.f ? v3 * v3 : 0.f;
        o.x = f2bf(v0); o.y = f2bf(v1); o.z = f2bf(v2); o.w = f2bf(v3);
        *(short4*)&C[(size_t)row * N + col] = o;
      }
    }
  } else {
    float* C = (float*)Cout;
#pragma unroll
    for (int m = 0; m < 8; ++m) {
      const int row = brow * 256 + wr * 128 + m * 16 + fr;
#pragma unroll
      for (int n = 0; n < 4; ++n) {
        const int col = bcol * 256 + wc * 64 + n * 16 + q * 4;
        const float4 bv = *(const float4*)&bias[col];
        float4 o;
        o.x = acc[m][n][0] + bv.x;
        o.y = acc[m][n][1] + bv.y;
        o.z = acc[m][n][2] + bv.z;
        o.w = acc[m][n][3] + bv.w;
        *(float4*)&C[(size_t)row * N + col] = o;
      }
    }
  }
#undef STAGE
}

// ---- launch -------------------------------------------------------------

extern "C" void kernel_launch(void* const* d_in, const int* in_sizes, int n_in,
                              void* d_out, int out_size, void* d_ws,
                              size_t ws_size, hipStream_t stream) {
  const float* x  = (const float*)d_in[0];
  const float* w1 = (const float*)d_in[1];
  const float* b1 = (const float*)d_in[2];
  const float* w2 = (const float*)d_in[3];
  const float* b2 = (const float*)d_in[4];
  float* out = (float*)d_out;

  const int H = in_sizes[2];            // 8192
  const int D = in_sizes[4];            // 2048
  const int M = in_sizes[0] / D;        // B*S = 8192

  short* xb  = (short*)d_ws;                 // M*D
  short* w1b = xb  + (size_t)M * D;          // H*D
  short* w2b = w1b + (size_t)H * D;          // D*H
  short* act = w2b + (size_t)D * H;          // M*H

  {
    int n4 = (M * D) / 4;
    cvt_f32_bf16<<<(n4 + 255) / 256, 256, 0, stream>>>(x, xb, n4);
    n4 = (H * D) / 4;
    cvt_f32_bf16<<<(n4 + 255) / 256, 256, 0, stream>>>(w1, w1b, n4);
    n4 = (D * H) / 4;
    cvt_f32_bf16<<<(n4 + 255) / 256, 256, 0, stream>>>(w2, w2b, n4);
  }

  // GEMM1: [M,D] @ [H,D]^T -> sqrelu -> act[M,H] (bf16)
  gemm_bt<0><<<(M / 256) * (H / 256), 512, 0, stream>>>(
      xb, w1b, b1, (void*)act, M, H, D);
  // GEMM2: [M,H] @ [D,H]^T -> + b2 -> out[M,D] (f32)
  gemm_bt<1><<<(M / 256) * (D / 256), 512, 0, stream>>>(
      act, w2b, b2, (void*)out, M, D, H);
}